// Round 4
// baseline (323.744 us; speedup 1.0000x reference)
//
#include <hip/hip_runtime.h>

#define BB 2
#define NPTS 100
#define PP 1024
#define NN 1125
#define NPAD 1152
#define NSCALE 4
#define NG 16
#define KPAD 5
#define CAMTHR 0.2f

#define R 25                              // rows per i-chunk
#define IC 45                             // i-chunks (IC*R == NN)
#define JT 5                              // j-tiles of 256
#define NBLOCKS (IC * BB * JT)            // 450 blocks, all co-resident (<=2/CU)
#define NWAVES (NBLOCKS * 4)              // 1800 waves
#define PSTRIDE (BB * NG * NPAD)
#define PSZ (IC * PSTRIDE)

#define N_ROWSUM (3 * BB * NN)            // 6750
#define N_INITV (BB * NG)                 // 32

// workspace layout (floats)
#define WS_BAR 0                              // 16 floats (64 B): 5 {cnt,flag} pairs
#define WS_ROWSUM 16                          // [3][BB][NPAD]  kk=0->blk8, 1->blk9, 2->blk10
#define WS_VS (WS_ROWSUM + 3 * BB * NPAD)     // [4][BB][NG][NPAD]  V0..V3 (V0 unused)
#define WS_P0 (WS_VS + 4 * BB * NG * NPAD)    // stage-10 partials
#define WS_P1 (WS_P0 + PSZ)                   // stage-9 partials
#define WS_P2 (WS_P1 + PSZ)                   // stage-8 partials

__device__ __forceinline__ float wave_sum(float s) {
#pragma unroll
    for (int m = 32; m > 0; m >>= 1) s += __shfl_xor(s, m, 64);
    return s;
}

// Grid barrier: one {cnt,flag} slot per use, pre-zeroed by memset each launch.
__device__ __forceinline__ void grid_bar(unsigned* bar, int slot) {
    __syncthreads();
    if (threadIdx.x == 0) {
        unsigned* cnt = bar + slot * 2;
        unsigned* flg = bar + slot * 2 + 1;
        unsigned old = __hip_atomic_fetch_add(cnt, 1u, __ATOMIC_ACQ_REL,
                                              __HIP_MEMORY_SCOPE_AGENT);
        if (old == NBLOCKS - 1) {
            __hip_atomic_store(flg, 1u, __ATOMIC_RELEASE, __HIP_MEMORY_SCOPE_AGENT);
        } else {
            while (!__hip_atomic_load(flg, __ATOMIC_ACQUIRE, __HIP_MEMORY_SCOPE_AGENT)) {
                __builtin_amdgcn_s_sleep(2);
            }
        }
    }
    __syncthreads();
}

// Stage multiply: block (ic,b,jt) computes partial[ic][b][g][j] over its 25-row window.
__device__ __forceinline__ void stage_phase(const float* __restrict__ A,
                                            float* __restrict__ ws, float* Wl,
                                            int blk, int kk, int s_in, int pofs) {
    int x = blockIdx.x;
    int jt = x % JT;
    int b = (x / JT) % BB;
    int ic = x / (JT * BB);
    int i0 = ic * R;
    const float* rs = ws + WS_ROWSUM + (kk * BB + b) * NPAD;
    const float* vin = ws + WS_VS + (size_t)(s_in * BB + b) * NG * NPAD;
    for (int idx = threadIdx.x; idx < R * NG; idx += 256) {
        int il = idx >> 4, g = idx & 15;
        Wl[idx] = vin[(size_t)g * NPAD + i0 + il] / rs[i0 + il];
    }
    __syncthreads();
    int j = jt * 256 + threadIdx.x;
    if (j < NN) {
        float acc[NG];
#pragma unroll
        for (int g = 0; g < NG; ++g) acc[g] = 0.f;
        const float* Ab = A + (((size_t)blk * BB + b) * NN + i0) * NN + j;
#pragma unroll
        for (int il = 0; il < R; ++il) {
            float a = Ab[(size_t)il * NN];
#pragma unroll
            for (int g = 0; g < NG; ++g) acc[g] += Wl[il * NG + g] * a;
        }
        int d = j - i0;
        if (d >= 0 && d < R) {            // identity term: diagonal chunk only
#pragma unroll
            for (int g = 0; g < NG; ++g) acc[g] += Wl[d * NG + g];
        }
        float* po = ws + pofs + (size_t)(ic * BB + b) * NG * NPAD + j;
#pragma unroll
        for (int g = 0; g < NG; ++g) po[(size_t)g * NPAD] = acc[g];
    }
}

// Coalesced non-redundant reduce of partials -> materialized V[s_out].
__device__ __forceinline__ void reduce_phase(float* __restrict__ ws, int pofs, int s_out) {
    int t = blockIdx.x * 256 + threadIdx.x;
    if (t < BB * NG * NPAD) {
        int j = t % NPAD;
        int g = (t / NPAD) % NG;
        int b = t / (NPAD * NG);
        if (j < NN) {
            const float* pp = ws + pofs + (size_t)(b * NG + g) * NPAD + j;
            float s = 0.f;
#pragma unroll
            for (int c = 0; c < IC; ++c) s += pp[(size_t)c * PSTRIDE];
            ws[WS_VS + ((size_t)(s_out * BB + b) * NG + g) * NPAD + j] = s;
        }
    }
}

// ---------------------------------------------------------------------------
// Mega kernel: rowsums+initv | S10 | R->V2 | S9 | R->V1 | S8, with 5 grid barriers.
__global__ __launch_bounds__(256, 2) void mega_kernel(const float* __restrict__ A,
                                                      const int* __restrict__ pos,
                                                      float* __restrict__ ws) {
    __shared__ float Wl[R * NG];
    unsigned* bar = (unsigned*)ws;
    int wave = threadIdx.x >> 6, lane = threadIdx.x & 63;
    int gwave = blockIdx.x * 4 + wave;

    // P0: rowsums (+1) of aug blocks 8..10 and initial vectors V3 (rows of norm aug11).
    for (int task = gwave; task < N_ROWSUM + N_INITV; task += NWAVES) {
        if (task < N_ROWSUM) {
            int i = task % NN;
            int b = (task / NN) % BB;
            int kk = task / (NN * BB);
            const float* row = A + (((size_t)(8 + kk) * BB + b) * NN + i) * NN;
            float s = 0.f;
#pragma unroll
            for (int k = 0; k < 17; ++k) s += row[lane + 64 * k];
            if (lane < NN - 17 * 64) s += row[lane + 17 * 64];
            s = wave_sum(s);
            if (lane == 0) ws[WS_ROWSUM + (kk * BB + b) * NPAD + i] = s + 1.0f;
        } else {
            int t = task - N_ROWSUM;
            int g = t % NG, b = t / NG;
            int r = NN - NPTS + pos[b * NG + g];
            const float* row = A + (((size_t)11 * BB + b) * NN + r) * NN;
            float s = 0.f;
#pragma unroll
            for (int k = 0; k < 17; ++k) s += row[lane + 64 * k];
            if (lane < NN - 17 * 64) s += row[lane + 17 * 64];
            s = wave_sum(s);
            float inv = 1.0f / (s + 1.0f);
            float* v = ws + WS_VS + ((size_t)(3 * BB + b) * NG + g) * NPAD;
            for (int j = lane; j < NN; j += 64)
                v[j] = (row[j] + (j == r ? 1.0f : 0.0f)) * inv;
        }
    }
    grid_bar(bar, 0);
    stage_phase(A, ws, Wl, 10, 2, 3, WS_P0);   // V3 -> P0
    grid_bar(bar, 1);
    reduce_phase(ws, WS_P0, 2);                // P0 -> V2
    grid_bar(bar, 2);
    stage_phase(A, ws, Wl, 9, 1, 2, WS_P1);    // V2 -> P1
    grid_bar(bar, 3);
    reduce_phase(ws, WS_P1, 1);                // P1 -> V1
    grid_bar(bar, 4);
    stage_phase(A, ws, Wl, 8, 0, 1, WS_P2);    // V1 -> P2 (reduced inside post)
}

// ---------------------------------------------------------------------------
// Post: per-image normalize, binarize, morph close (zero-pad), bbox.
// s==0 images reduce V0 from the stage-8 partials (coalesced over pixels).
__global__ __launch_bounds__(1024) void post_kernel(const float* __restrict__ ws,
                                                    float* __restrict__ out) {
    __shared__ float redA[1024];
    __shared__ float redB[1024];
    __shared__ float img[1024];
    __shared__ float tmp[1024];
    int idx = blockIdx.x;                 // (b*NG+g)*NSCALE + s
    int s = idx % NSCALE;
    int g = (idx / NSCALE) % NG;
    int b = idx / (NSCALE * NG);
    int p = threadIdx.x;                  // 0..1023
    float cam;
    if (s == 0) {
        const float* pp = ws + WS_P2 + (size_t)(b * NG + g) * NPAD + 1 + p;
        float t = 0.f;
#pragma unroll
        for (int c = 0; c < IC; ++c) t += pp[(size_t)c * PSTRIDE];
        cam = t;
    } else {
        cam = ws[WS_VS + ((size_t)(s * BB + b) * NG + g) * NPAD + 1 + p];
    }
    redA[p] = cam;
    redB[p] = cam;
    __syncthreads();
    for (int st = 512; st > 0; st >>= 1) {
        if (p < st) {
            redA[p] = fminf(redA[p], redA[p + st]);
            redB[p] = fmaxf(redB[p], redB[p + st]);
        }
        __syncthreads();
    }
    float mn = redA[0], mx = redB[0];
    float camn = (cam - mn) / (mx - mn + 1e-6f);
    out[(size_t)idx * PP + p] = camn;
    float bin = camn >= CAMTHR ? 1.0f : 0.0f;
    __syncthreads();
    img[p] = bin;
    __syncthreads();
    int y = p >> 5, x = p & 31;
    float m = 0.f;
    for (int dx = -KPAD; dx <= KPAD; ++dx) {
        int xx = x + dx;
        if (xx >= 0 && xx < 32) m = fmaxf(m, img[(y << 5) | xx]);
    }
    tmp[p] = m;
    __syncthreads();
    m = 0.f;
    for (int dy = -KPAD; dy <= KPAD; ++dy) {
        int yy = y + dy;
        if (yy >= 0 && yy < 32) m = fmaxf(m, tmp[(yy << 5) | x]);
    }
    __syncthreads();
    img[p] = m;                           // dilated
    __syncthreads();
    float e;
    if (x < KPAD || x > 31 - KPAD) {
        e = 0.f;
    } else {
        e = 1e30f;
        for (int dx = -KPAD; dx <= KPAD; ++dx) e = fminf(e, img[(y << 5) | (x + dx)]);
    }
    tmp[p] = e;
    __syncthreads();
    float ev;
    if (y < KPAD || y > 31 - KPAD) {
        ev = 0.f;
    } else {
        ev = 1e30f;
        for (int dy = -KPAD; dy <= KPAD; ++dy) ev = fminf(ev, tmp[((y + dy) << 5) | x]);
    }
    out[(size_t)(BB * NG * NSCALE) * PP + (size_t)idx * PP + p] = ev;
    bool fg = ev > 0.5f;
    redA[p] = fg ? (float)x : 1e9f;
    redB[p] = fg ? (float)x : -1e9f;
    __syncthreads();
    for (int st = 512; st > 0; st >>= 1) {
        if (p < st) {
            redA[p] = fminf(redA[p], redA[p + st]);
            redB[p] = fmaxf(redB[p], redB[p + st]);
        }
        __syncthreads();
    }
    float xmin = redA[0], xmax = redB[0];
    __syncthreads();
    redA[p] = fg ? (float)y : 1e9f;
    redB[p] = fg ? (float)y : -1e9f;
    __syncthreads();
    for (int st = 512; st > 0; st >>= 1) {
        if (p < st) {
            redA[p] = fminf(redA[p], redA[p + st]);
            redB[p] = fmaxf(redB[p], redB[p + st]);
        }
        __syncthreads();
    }
    if (p == 0) {
        float ymin = redA[0], ymax = redB[0];
        float* bb = out + (size_t)(BB * NG * NSCALE) * PP * 2 + (size_t)idx * 4;
        if (xmax < -1e8f) {
            bb[0] = 0.f; bb[1] = 0.f; bb[2] = 1.f; bb[3] = 1.f;
        } else {
            bb[0] = xmin; bb[1] = ymin; bb[2] = xmax; bb[3] = ymax;
        }
    }
}

extern "C" void kernel_launch(void* const* d_in, const int* in_sizes, int n_in,
                              void* d_out, int out_size, void* d_ws, size_t ws_size,
                              hipStream_t stream) {
    const float* A = (const float*)d_in[0];
    const int* pos = (const int*)d_in[1];
    float* out = (float*)d_out;
    float* ws = (float*)d_ws;

    // zero the 5 barrier slots (deterministic across graph replays)
    hipMemsetAsync(ws, 0, 64, stream);
    mega_kernel<<<NBLOCKS, 256, 0, stream>>>(A, pos, ws);
    post_kernel<<<BB * NG * NSCALE, 1024, 0, stream>>>(ws, out);
}

// Round 5
// 52.674 us; speedup vs baseline: 6.1462x; 6.1462x over previous
//
#include <hip/hip_runtime.h>

#define BB 2
#define NPTS 100
#define PP 1024
#define NN 1125
#define NPAD 1152
#define NSCALE 4
#define NG 16
#define KPAD 5
#define CAMTHR 0.2f

#define R 25                              // rows per i-chunk
#define IC 45                             // i-chunks (IC*R == NN)
#define JT 5                              // j-tiles of 256
#define NBLOCKS (IC * BB * JT)            // 450

#define TJ (NPAD * 16)                    // transposed per-(c,b) pitch: j*16+g
#define CSTRIDE_T (BB * TJ)               // c-stride, transposed layout
#define PSZ_T (IC * CSTRIDE_T)
#define PSTRIDE_O (BB * NG * NPAD)        // c-stride, old layout (for P2/post)
#define PSZ_O (IC * PSTRIDE_O)

#define N_ROWSUM (3 * BB * NN)            // 6750
#define N_INITV (BB * NG)                 // 32

// workspace layout (floats)
#define WS_ROWSUM 0                           // [3][BB][NPAD]  kk=0->blk8, 1->blk9, 2->blk10
#define WS_VS (WS_ROWSUM + 3 * BB * NPAD)     // [4][BB][NG][NPAD]  V1..V3 materialized
#define WS_P0 (WS_VS + 4 * BB * NG * NPAD)    // stage-10 partials, transposed
#define WS_P1 (WS_P0 + PSZ_T)                 // stage-9 partials, transposed
#define WS_P2 (WS_P1 + PSZ_T)                 // stage-8 partials, OLD layout (for post)

__device__ __forceinline__ float wave_sum(float s) {
#pragma unroll
    for (int m = 32; m > 0; m >>= 1) s += __shfl_xor(s, m, 64);
    return s;
}

// ---------------------------------------------------------------------------
// K1: wave-per-row. Tasks 0..6749: rowsums (+1) of aug blocks 8..10.
//     Tasks 6750..6781: initial vectors V3 = row r of normalized aug[11].
__global__ __launch_bounds__(256) void prep_kernel(const float* __restrict__ A,
                                                   const int* __restrict__ pos,
                                                   float* __restrict__ ws) {
    int wave = threadIdx.x >> 6;
    int lane = threadIdx.x & 63;
    int task = blockIdx.x * 4 + wave;
    if (task < N_ROWSUM) {
        int i = task % NN;
        int b = (task / NN) % BB;
        int kk = task / (NN * BB);
        const float* row = A + (((size_t)(8 + kk) * BB + b) * NN + i) * NN;
        float s = 0.f;
#pragma unroll
        for (int k = 0; k < 17; ++k) s += row[lane + 64 * k];
        if (lane < NN - 17 * 64) s += row[lane + 17 * 64];
        s = wave_sum(s);
        if (lane == 0) ws[WS_ROWSUM + (kk * BB + b) * NPAD + i] = s + 1.0f;
    } else if (task < N_ROWSUM + N_INITV) {
        int t = task - N_ROWSUM;
        int g = t % NG;
        int b = t / NG;
        int r = NN - NPTS + pos[b * NG + g];
        const float* row = A + (((size_t)11 * BB + b) * NN + r) * NN;
        float s = 0.f;
#pragma unroll
        for (int k = 0; k < 17; ++k) s += row[lane + 64 * k];
        if (lane < NN - 17 * 64) s += row[lane + 17 * 64];
        s = wave_sum(s);
        float inv = 1.0f / (s + 1.0f);
        float* v = ws + WS_VS + ((size_t)(3 * BB + b) * NG + g) * NPAD;
        for (int j = lane; j < NN; j += 64)
            v[j] = (row[j] + (j == r ? 1.0f : 0.0f)) * inv;
    }
}

// ---------------------------------------------------------------------------
// K2: one stage. Block (ic,b,jt):
//  W-window: either from materialized vin [b][g][NPAD] (stage 10), or fused
//  coalesced reduce of prevP (transposed [c][b][j*16+g]: 45 contiguous 1.6KB
//  runs per block); jt==0 blocks also materialize V_in for post (tiny).
//  Multiply: partial[g][j] = sum_il w*A[i0+il][j] (+ diagonal identity term),
//  written transposed (outT=1) or old-layout (outT=0, consumed by post).
__global__ __launch_bounds__(256) void stage_kernel(
        const float* __restrict__ A, const float* __restrict__ rsb,
        const float* __restrict__ vin, const float* __restrict__ prevP,
        float* __restrict__ curP, float* __restrict__ vout, int blk, int outT) {
    __shared__ float Wl[R * NG];          // [il][g]
    int x = blockIdx.x;
    int jt = x % JT;
    int b = (x / JT) % BB;
    int ic = x / (JT * BB);
    int i0 = ic * R;
    const float* rs = rsb + b * NPAD;
    if (prevP) {
        for (int idx = threadIdx.x; idx < R * NG; idx += 256) {
            const float* pp = prevP + (size_t)b * TJ + i0 * 16 + idx;
            float s = 0.f;
#pragma unroll
            for (int c = 0; c < IC; ++c) s += pp[(size_t)c * CSTRIDE_T];
            int il = idx >> 4, g = idx & 15;
            if (jt == 0)
                vout[((size_t)(b * NG) + g) * NPAD + i0 + il] = s;
            Wl[idx] = s / rs[i0 + il];
        }
    } else {
        for (int idx = threadIdx.x; idx < R * NG; idx += 256) {
            int il = idx >> 4, g = idx & 15;
            Wl[idx] = vin[((size_t)(b * NG) + g) * NPAD + i0 + il] / rs[i0 + il];
        }
    }
    __syncthreads();
    int j = jt * 256 + threadIdx.x;
    if (j >= NN) return;
    float acc[NG];
#pragma unroll
    for (int g = 0; g < NG; ++g) acc[g] = 0.f;
    const float* Ab = A + (((size_t)blk * BB + b) * NN + i0) * NN + j;
#pragma unroll
    for (int il = 0; il < R; ++il) {
        float a = Ab[(size_t)il * NN];
#pragma unroll
        for (int g = 0; g < NG; ++g) acc[g] += Wl[il * NG + g] * a;
    }
    int d = j - i0;
    if (d >= 0 && d < R) {                // identity term: diagonal chunk only
#pragma unroll
        for (int g = 0; g < NG; ++g) acc[g] += Wl[d * NG + g];
    }
    if (outT) {
        float* po = curP + (size_t)(ic * BB + b) * TJ + (size_t)j * 16;
#pragma unroll
        for (int g = 0; g < NG; g += 4)
            *(float4*)(po + g) = make_float4(acc[g], acc[g + 1], acc[g + 2], acc[g + 3]);
    } else {
        float* po = curP + (size_t)(ic * BB + b) * NG * NPAD + j;
#pragma unroll
        for (int g = 0; g < NG; ++g) po[(size_t)g * NPAD] = acc[g];
    }
}

// ---------------------------------------------------------------------------
// K3: per-image normalize, binarize, morph close (zero-pad), bbox.
//     s==0 images reduce V0 from the stage-8 partials (old layout, coalesced).
__global__ __launch_bounds__(1024) void post_kernel(const float* __restrict__ ws,
                                                    float* __restrict__ out) {
    __shared__ float redA[1024];
    __shared__ float redB[1024];
    __shared__ float img[1024];
    __shared__ float tmp[1024];
    int idx = blockIdx.x;                 // (b*NG+g)*NSCALE + s
    int s = idx % NSCALE;
    int g = (idx / NSCALE) % NG;
    int b = idx / (NSCALE * NG);
    int p = threadIdx.x;                  // 0..1023
    float cam;
    if (s == 0) {
        const float* pp = ws + WS_P2 + (size_t)(b * NG + g) * NPAD + 1 + p;
        float t = 0.f;
#pragma unroll
        for (int c = 0; c < IC; ++c) t += pp[(size_t)c * PSTRIDE_O];
        cam = t;
    } else {
        cam = ws[WS_VS + ((size_t)(s * BB + b) * NG + g) * NPAD + 1 + p];
    }
    redA[p] = cam;
    redB[p] = cam;
    __syncthreads();
    for (int st = 512; st > 0; st >>= 1) {
        if (p < st) {
            redA[p] = fminf(redA[p], redA[p + st]);
            redB[p] = fmaxf(redB[p], redB[p + st]);
        }
        __syncthreads();
    }
    float mn = redA[0], mx = redB[0];
    float camn = (cam - mn) / (mx - mn + 1e-6f);
    out[(size_t)idx * PP + p] = camn;
    float bin = camn >= CAMTHR ? 1.0f : 0.0f;
    __syncthreads();
    img[p] = bin;
    __syncthreads();
    int y = p >> 5, x = p & 31;
    float m = 0.f;
    for (int dx = -KPAD; dx <= KPAD; ++dx) {
        int xx = x + dx;
        if (xx >= 0 && xx < 32) m = fmaxf(m, img[(y << 5) | xx]);
    }
    tmp[p] = m;
    __syncthreads();
    m = 0.f;
    for (int dy = -KPAD; dy <= KPAD; ++dy) {
        int yy = y + dy;
        if (yy >= 0 && yy < 32) m = fmaxf(m, tmp[(yy << 5) | x]);
    }
    __syncthreads();
    img[p] = m;                           // dilated
    __syncthreads();
    float e;
    if (x < KPAD || x > 31 - KPAD) {
        e = 0.f;
    } else {
        e = 1e30f;
        for (int dx = -KPAD; dx <= KPAD; ++dx) e = fminf(e, img[(y << 5) | (x + dx)]);
    }
    tmp[p] = e;
    __syncthreads();
    float ev;
    if (y < KPAD || y > 31 - KPAD) {
        ev = 0.f;
    } else {
        ev = 1e30f;
        for (int dy = -KPAD; dy <= KPAD; ++dy) ev = fminf(ev, tmp[((y + dy) << 5) | x]);
    }
    out[(size_t)(BB * NG * NSCALE) * PP + (size_t)idx * PP + p] = ev;
    bool fg = ev > 0.5f;
    redA[p] = fg ? (float)x : 1e9f;
    redB[p] = fg ? (float)x : -1e9f;
    __syncthreads();
    for (int st = 512; st > 0; st >>= 1) {
        if (p < st) {
            redA[p] = fminf(redA[p], redA[p + st]);
            redB[p] = fmaxf(redB[p], redB[p + st]);
        }
        __syncthreads();
    }
    float xmin = redA[0], xmax = redB[0];
    __syncthreads();
    redA[p] = fg ? (float)y : 1e9f;
    redB[p] = fg ? (float)y : -1e9f;
    __syncthreads();
    for (int st = 512; st > 0; st >>= 1) {
        if (p < st) {
            redA[p] = fminf(redA[p], redA[p + st]);
            redB[p] = fmaxf(redB[p], redB[p + st]);
        }
        __syncthreads();
    }
    if (p == 0) {
        float ymin = redA[0], ymax = redB[0];
        float* bb = out + (size_t)(BB * NG * NSCALE) * PP * 2 + (size_t)idx * 4;
        if (xmax < -1e8f) {
            bb[0] = 0.f; bb[1] = 0.f; bb[2] = 1.f; bb[3] = 1.f;
        } else {
            bb[0] = xmin; bb[1] = ymin; bb[2] = xmax; bb[3] = ymax;
        }
    }
}

extern "C" void kernel_launch(void* const* d_in, const int* in_sizes, int n_in,
                              void* d_out, int out_size, void* d_ws, size_t ws_size,
                              hipStream_t stream) {
    const float* A = (const float*)d_in[0];
    const int* pos = (const int*)d_in[1];
    float* out = (float*)d_out;
    float* ws = (float*)d_ws;

    const float* rs2 = ws + WS_ROWSUM + 2 * BB * NPAD;   // block 10
    const float* rs1 = ws + WS_ROWSUM + 1 * BB * NPAD;   // block 9
    const float* rs0 = ws + WS_ROWSUM + 0 * BB * NPAD;   // block 8
    float* VS3 = ws + WS_VS + 3 * BB * NG * NPAD;
    float* VS2 = ws + WS_VS + 2 * BB * NG * NPAD;
    float* VS1 = ws + WS_VS + 1 * BB * NG * NPAD;

    prep_kernel<<<(N_ROWSUM + N_INITV + 3) / 4, 256, 0, stream>>>(A, pos, ws);
    // S10: V3 -> P0 (transposed)
    stage_kernel<<<NBLOCKS, 256, 0, stream>>>(A, rs2, VS3, nullptr,
                                              ws + WS_P0, nullptr, 10, 1);
    // S9: fused reduce(P0) -> V2 (jt==0) ; multiply -> P1 (transposed)
    stage_kernel<<<NBLOCKS, 256, 0, stream>>>(A, rs1, nullptr, ws + WS_P0,
                                              ws + WS_P1, VS2, 9, 1);
    // S8: fused reduce(P1) -> V1 (jt==0) ; multiply -> P2 (old layout)
    stage_kernel<<<NBLOCKS, 256, 0, stream>>>(A, rs0, nullptr, ws + WS_P1,
                                              ws + WS_P2, VS1, 8, 0);
    post_kernel<<<BB * NG * NSCALE, 1024, 0, stream>>>(ws, out);
}